// Round 5
// baseline (246.039 us; speedup 1.0000x reference)
//
#include <hip/hip_runtime.h>
#include <climits>

#define HW 262144          // 512*512
#define IW 512
#define RN 725             // virtual rotated canvas side
#define NSEG 256
#define CH_OFF 1536
#define TH_OFF 116736
#define XY_OFF 485376
#define NBLK 256           // grad tiles per plane; minmax partial count
#define THP 24             // pixel splits in k_thist
#define CHP 64             // pixel splits, color-hist role (r19: 32->64)
#define RSP 64             // pixel splits, region/bbox role

// grad tile geometry (r16): output tile 64x16; rotated source box 24x72 at (-156,-156).
#define ASTR 67
#define RSTR 73
#define ROFF 156

static __device__ __forceinline__ float rtap_l(const float* __restrict__ Rt,
                                               int rx0, int ry0, int cx, int cy) {
    if (cx < 0 || cx >= RN || cy < 0 || cy >= RN) return 0.f;
    const float cs = 0.7071067811865476f;
    float xg = (float)cx - 362.0f;
    float yg = (float)cy - 362.0f;
    float xi = cs * xg - cs * yg + 255.5f;
    float yi = cs * xg + cs * yg + 255.5f;
    int xs = (int)rintf(xi);
    int ys = (int)rintf(yi);
    if (xs < 0 || xs >= IW || ys < 0 || ys >= IW) return 0.f;
    return Rt[(ys - ry0) * RSTR + (xs - rx0)];
}

// block-level min/max of map m's NBLK partials; all threads get (mn,mx)
static __device__ __forceinline__ void mm_of_map(const float* __restrict__ pmin,
                                                 const float* __restrict__ pmax,
                                                 int m, float* slo, float* shi,
                                                 float& mn, float& mx) {
    int tid = threadIdx.x;
    float lo = 3.4e38f, hi = -3.4e38f;
    for (int i = tid; i < NBLK; i += 256) {
        lo = fminf(lo, pmin[m * NBLK + i]);
        hi = fmaxf(hi, pmax[m * NBLK + i]);
    }
    slo[tid] = lo; shi[tid] = hi;
    __syncthreads();
    for (int off = 128; off > 0; off >>= 1) {
        if (tid < off) {
            slo[tid] = fminf(slo[tid], slo[tid + off]);
            shi[tid] = fmaxf(shi[tid], shi[tid + off]);
        }
        __syncthreads();
    }
    mn = slo[0]; mx = shi[0];
    __syncthreads();
}

// ==== K1 (r19): grad || color-hist || region/bbox, role-interleaved ====
// Even blocks: grad (1536). Odd blocks: color-hist (1152) then region (384).
// Interleave -> heterogeneous CU mix (grad VALU/mem-heavy, hists LDS-atomic-heavy).
// LDS union = 25.6KB (color-hist cnt) -> 6 blocks/CU all roles (r3's 30.7KB
// merge regression fixed). All roles independent: hist roles read int32 lab;
// rs/bbox are deterministic partials (no global atomics, no init chores).
__global__ __launch_bounds__(256) void k_front(
    const float* __restrict__ img, const int* __restrict__ lab,
    float* __restrict__ gmaps, float* __restrict__ pmin, float* __restrict__ pmax,
    unsigned char* __restrict__ lab8, unsigned* __restrict__ chp,
    unsigned* __restrict__ rsp, int* __restrict__ bxmin, int* __restrict__ bxmax,
    int* __restrict__ bymin, int* __restrict__ bymax)
{
    __shared__ __align__(16) unsigned char smem[25600];
    int bxid = blockIdx.x;
    int tid = threadIdx.x;
    if ((bxid & 1) == 0) {
        // ---- grad role: u in [0,1536): tile (u&255), plane bc=(u>>8) ----
        int u = bxid >> 1;
        int tile = u & 255;
        int bc = u >> 8;
        float* At = (float*)smem;                               // 1206 f
        float* Rt = At + 18 * ASTR;                             // 1752 f
        float (*slo)[256] = (float (*)[256])(Rt + 24 * RSTR);   // 4*256 f
        float (*shi)[256] = slo + 4;                            // 4*256 f (20024 B)
        // u8 label pack for k_thist: 256 blocks/plane * 256 thr * 4 == HW
        {
            int i = tile * 256 + tid;
            int4 l = ((const int4*)(lab + (size_t)bc * HW))[i];
            unsigned v = (unsigned)(l.x & 255) | ((unsigned)(l.y & 255) << 8) |
                         ((unsigned)(l.z & 255) << 16) | ((unsigned)(l.w & 255) << 24);
            ((unsigned*)(lab8 + (size_t)bc * HW))[i] = v;
        }
        int tx0 = (tile & 7) << 6;
        int ty0 = (tile >> 3) << 4;
        const float* im = img + (size_t)bc * HW;
        int lane = tid & 63, wr = tid >> 6;
        for (int r = wr; r < 18; r += 4) {
            int gy = ty0 - 1 + r;
            bool yok = (gy >= 0 && gy < IW);
            int gx = tx0 - 1 + lane;
            At[r * ASTR + lane] = (yok && gx >= 0 && gx < IW) ? im[gy * IW + gx] : 0.f;
            if (lane < 2) {
                int gx2 = gx + 64;
                At[r * ASTR + lane + 64] = (yok && gx2 >= 0 && gx2 < IW) ? im[gy * IW + gx2] : 0.f;
            }
        }
        for (int r = wr; r < 24; r += 4) {
            int gy = ty0 - ROFF + r;
            bool yok = (gy >= 0 && gy < IW);
            int gx = tx0 - ROFF + lane;
            Rt[r * RSTR + lane] = (yok && gx >= 0 && gx < IW) ? im[gy * IW + gx] : 0.f;
            if (lane < 8) {
                int gx2 = gx + 64;
                Rt[r * RSTR + lane + 64] = (yok && gx2 >= 0 && gx2 < IW) ? im[gy * IW + gx2] : 0.f;
            }
        }
        __syncthreads();
        const float cs = 0.7071067811865476f;
        int rx0 = tx0 - ROFF, ry0 = ty0 - ROFF;
        float mn0 = 3.4e38f, mx0 = -3.4e38f, mn1 = 3.4e38f, mx1 = -3.4e38f;
        float mn2 = 3.4e38f, mx2 = -3.4e38f, mn3 = 3.4e38f, mx3 = -3.4e38f;
        #pragma unroll
        for (int it = 0; it < 4; ++it) {
            int ly = wr * 4 + it;
            int x = tx0 + lane, y = ty0 + ly;
            int p = y * IW + x;
            const float* Ar = At + ly * ASTR + lane;
            float a  = Ar[0],            b2 = Ar[1],            c2 = Ar[2];
            float d2 = Ar[ASTR],                                 e2 = Ar[ASTR + 2];
            float f2 = Ar[2 * ASTR],     h2 = Ar[2 * ASTR + 1], i9 = Ar[2 * ASTR + 2];
            float g0 = -3.f*a + 3.f*c2 + 10.f*d2 + 10.f*e2 - 3.f*f2 + 3.f*i9;
            float g1 = -3.f*a + 10.f*b2 - 3.f*c2 + 3.f*f2 + 10.f*h2 + 3.f*i9;
            gmaps[((size_t)(bc*2+0))*HW + p] = g0;
            gmaps[((size_t)(bc*2+1))*HW + p] = g1;
            float xgc = (float)(x + 105) - 512.5f;
            float ygc = (float)(y + 105) - 512.5f;
            float t1 = cs * xgc, t2 = cs * ygc;
            float xi = (t1 + t2) + 362.0f;
            float yi = (-t1 + t2) + 362.0f;
            int xn = (int)rintf(xi);
            int yn = (int)rintf(yi);
            float r0 = 0.f, r1 = 0.f;
            if (xn >= 0 && xn < RN && yn >= 0 && yn < RN) {
                float ra = rtap_l(Rt, rx0, ry0, xn-1, yn-1);
                float rb = rtap_l(Rt, rx0, ry0, xn,   yn-1);
                float rc = rtap_l(Rt, rx0, ry0, xn+1, yn-1);
                float rd = rtap_l(Rt, rx0, ry0, xn-1, yn);
                float re = rtap_l(Rt, rx0, ry0, xn+1, yn);
                float rf = rtap_l(Rt, rx0, ry0, xn-1, yn+1);
                float rh = rtap_l(Rt, rx0, ry0, xn,   yn+1);
                float ri = rtap_l(Rt, rx0, ry0, xn+1, yn+1);
                r0 = -3.f*ra + 3.f*rc + 10.f*rd + 10.f*re - 3.f*rf + 3.f*ri;
                r1 = -3.f*ra + 10.f*rb - 3.f*rc + 3.f*rf + 10.f*rh + 3.f*ri;
            }
            gmaps[((size_t)(12 + bc*2+0))*HW + p] = r0;
            gmaps[((size_t)(12 + bc*2+1))*HW + p] = r1;
            mn0 = fminf(mn0, g0); mx0 = fmaxf(mx0, g0);
            mn1 = fminf(mn1, g1); mx1 = fmaxf(mx1, g1);
            mn2 = fminf(mn2, r0); mx2 = fmaxf(mx2, r0);
            mn3 = fminf(mn3, r1); mx3 = fmaxf(mx3, r1);
        }
        slo[0][tid] = mn0; shi[0][tid] = mx0;
        slo[1][tid] = mn1; shi[1][tid] = mx1;
        slo[2][tid] = mn2; shi[2][tid] = mx2;
        slo[3][tid] = mn3; shi[3][tid] = mx3;
        __syncthreads();
        for (int off = 128; off > 0; off >>= 1) {
            if (tid < off) {
                #pragma unroll
                for (int k = 0; k < 4; ++k) {
                    slo[k][tid] = fminf(slo[k][tid], slo[k][tid + off]);
                    shi[k][tid] = fmaxf(shi[k][tid], shi[k][tid + off]);
                }
            }
            __syncthreads();
        }
        if (tid < 4) {
            int m = (tid < 2) ? (bc*2 + tid) : (12 + bc*2 + (tid - 2));
            pmin[m * NBLK + tile] = slo[tid][0];
            pmax[m * NBLK + tile] = shi[tid][0];
        }
    } else {
        int v = bxid >> 1;     // [0,1536)
        if (v < 18 * CHP) {
            // ---- color-hist role: row gy=(b*3+g)*3+c, split sp ----
            int gy = v / CHP;
            int sp = v - gy * CHP;
            int c = gy % 3;
            int bg = gy / 3;
            int b = bg / 3;
            unsigned* cnt = (unsigned*)smem;   // 6400 u32 = 25600 B
            for (int i = tid; i < NSEG * 25; i += 256) cnt[i] = 0;
            __syncthreads();
            const float4* ip = (const float4*)(img + ((size_t)b * 3 + c) * HW);
            const int4* lp = (const int4*)(lab + (size_t)bg * HW);
            for (int i = sp * 256 + tid; i < HW / 4; i += 256 * CHP) {
                float4 v4 = ip[i];
                int4 l4 = lp[i];
                int l0 = l4.x & 255, l1 = l4.y & 255, l2 = l4.z & 255, l3 = l4.w & 255;
                int b0 = (int)((float)l0 * 25.0f + v4.x * 24.0f);
                int b1 = (int)((float)l1 * 25.0f + v4.y * 24.0f);
                int b2 = (int)((float)l2 * 25.0f + v4.z * 24.0f);
                int b3 = (int)((float)l3 * 25.0f + v4.w * 24.0f);
                b0 = min(max(b0, 0), 6399); b1 = min(max(b1, 0), 6399);
                b2 = min(max(b2, 0), 6399); b3 = min(max(b3, 0), 6399);
                atomicAdd(&cnt[b0], 1u); atomicAdd(&cnt[b1], 1u);
                atomicAdd(&cnt[b2], 1u); atomicAdd(&cnt[b3], 1u);
            }
            __syncthreads();
            unsigned* dst = chp + ((size_t)gy * CHP + sp) * 6400;
            for (int i = tid; i < NSEG * 25; i += 256) dst[i] = cnt[i];
        } else {
            // ---- region/bbox role: plane bg, split sp; deterministic partials ----
            int w = v - 18 * CHP;          // [0,384)
            int bg = w / RSP;
            int sp = w - bg * RSP;
            unsigned* rcnt = (unsigned*)smem;          // 256
            int* sxmin = (int*)(rcnt + NSEG);          // 4x256 (5120 B total)
            int* sxmax = sxmin + NSEG;
            int* symin = sxmax + NSEG;
            int* symax = symin + NSEG;
            rcnt[tid] = 0; sxmin[tid] = INT_MAX; sxmax[tid] = INT_MIN;
            symin[tid] = INT_MAX; symax[tid] = INT_MIN;
            __syncthreads();
            const int4* lp = (const int4*)(lab + (size_t)bg * HW);
            for (int i = sp * 256 + tid; i < HW / 4; i += 256 * RSP) {
                int4 l4 = lp[i];
                int l0 = l4.x & 255, l1 = l4.y & 255, l2 = l4.z & 255, l3 = l4.w & 255;
                int p = i << 2;
                int y = p >> 9, x = p & 511;
                atomicAdd(&rcnt[l0], 1u); atomicAdd(&rcnt[l1], 1u);
                atomicAdd(&rcnt[l2], 1u); atomicAdd(&rcnt[l3], 1u);
                atomicMin(&sxmin[l0], x);     atomicMax(&sxmax[l0], x);
                atomicMin(&sxmin[l1], x + 1); atomicMax(&sxmax[l1], x + 1);
                atomicMin(&sxmin[l2], x + 2); atomicMax(&sxmax[l2], x + 2);
                atomicMin(&sxmin[l3], x + 3); atomicMax(&sxmax[l3], x + 3);
                atomicMin(&symin[l0], y); atomicMax(&symax[l0], y);
                atomicMin(&symin[l1], y); atomicMax(&symax[l1], y);
                atomicMin(&symin[l2], y); atomicMax(&symax[l2], y);
                atomicMin(&symin[l3], y); atomicMax(&symax[l3], y);
            }
            __syncthreads();
            size_t pi = (size_t)(bg * RSP + sp) * NSEG + tid;
            rsp[pi] = rcnt[tid];
            bxmin[pi] = sxmin[tid]; bxmax[pi] = sxmax[tid];
            bymin[pi] = symin[tid]; bymax[pi] = symax[tid];
        }
    }
}

// ---- texture histogram, high-occupancy (r18): one (map, lab-group) hist/block ----
__global__ __launch_bounds__(256) void k_thist(
    const float* __restrict__ maps, const unsigned char* __restrict__ lab8,
    const float* __restrict__ pmin, const float* __restrict__ pmax,
    unsigned* __restrict__ thp)
{
    __shared__ unsigned cnt[5120];     // [0,2560) pos bins, [2560,5120) neg
    __shared__ float slo[256], shi[256];
    int gy = blockIdx.y;               // [0,72): (r*3 + gi)
    int split = blockIdx.x;            // [0,THP)
    int gi = gy % 3;
    int r = gy / 3;
    int base = r & 1;
    int bd = r >> 1;
    int d = bd & 1;
    int bc = bd >> 1;
    int b = bc / 3;
    int m = base * 12 + bc * 2 + d;
    float mn, mx;
    mm_of_map(pmin, pmax, m, slo, shi, mn, mx);
    for (int i = threadIdx.x; i < 5120; i += 256) cnt[i] = 0;
    __syncthreads();
    float hminp = fmaxf(mn, 0.f), denp = fmaxf(mx, 0.f) - hminp;
    float hminn = fminf(mn, 0.f), denn = fminf(mx, 0.f) - hminn;
    const float4* src = (const float4*)(maps + (size_t)m * HW);
    const unsigned* lp = (const unsigned*)(lab8 + (size_t)(b * 3 + gi) * HW);
    for (int i = split * 256 + threadIdx.x; i < HW / 4; i += 256 * THP) {
        float4 v4 = src[i];
        unsigned l4 = lp[i];
#define TH1(V, SH)                                                     \
        {                                                              \
            float v = (V);                                             \
            bool ge = (v >= 0.f);                                      \
            float hm = ge ? hminp : hminn;                             \
            float dn = ge ? denp : denn;                               \
            float t9 = ((v - hm) / dn) * 9.0f;                         \
            int bi = (int)((float)((l4 >> SH) & 255u) * 10.0f + t9);   \
            bi = min(max(bi, 0), 2559);                                \
            atomicAdd(&cnt[(ge ? 0 : 2560) + bi], 1u);                 \
        }
        TH1(v4.x, 0) TH1(v4.y, 8) TH1(v4.z, 16) TH1(v4.w, 24)
#undef TH1
    }
    __syncthreads();
    unsigned* dst = thp + ((size_t)(gy * THP + split)) * 5120;
    for (int i = threadIdx.x; i < 5120; i += 256) dst[i] = cnt[i];
}

// ---- fused final: th chunked-reduce + sign-completion + normalize (bx<288);
//      ch partial-reduce + rs + xywh (else). rs computed from rsp partials in
//      BOTH branches (no cross-branch ordering through out[]). ----
__global__ __launch_bounds__(256) void k_thfinal(
    const unsigned* __restrict__ thp, const unsigned* __restrict__ chp,
    const unsigned* __restrict__ rsp,
    const float* __restrict__ pmin, const float* __restrict__ pmax,
    const int* __restrict__ bxmin, const int* __restrict__ bxmax,
    const int* __restrict__ bymin, const int* __restrict__ bymax,
    float* __restrict__ out)
{
    int tid = threadIdx.x;
    int bx = blockIdx.x;
    if (bx < 288) {
        __shared__ unsigned hist[1280];    // [0,640) pos, [640,1280) neg, 64 labels
        __shared__ unsigned srs[64];
        __shared__ float slo[256], shi[256];
        int gy = bx >> 2;
        int ck = bx & 3;
        int l0 = ck << 6;                  // first label of chunk
        int gi = gy % 3; int r = gy / 3; int base = r & 1;
        int bd = r >> 1; int d = bd & 1; int bc = bd >> 1;
        int b = bc / 3, c = bc - b * 3;
        int m = base * 12 + bc * 2 + d;
        int bg = b * 3 + gi;
        float mn, mx;
        mm_of_map(pmin, pmax, m, slo, shi, mn, mx);
        int g0off = l0 * 10;
        for (int i = tid; i < 1280; i += 256) {
            int g = (i < 640) ? (g0off + i) : (2560 + g0off + (i - 640));
            unsigned s = 0;
            #pragma unroll 4
            for (int p = 0; p < THP; ++p) s += thp[((size_t)(gy * THP + p)) * 5120 + g];
            hist[i] = s;
        }
        if (tid < 64) {
            unsigned s = 0;
            #pragma unroll 4
            for (int p = 0; p < RSP; ++p) s += rsp[((size_t)(bg * RSP + p)) * NSEG + l0 + tid];
            srs[tid] = s;
        }
        __syncthreads();
        if (tid < 64) {
            int l = l0 + tid;   // this chunk's labels: sign-completion
            unsigned nge = 0;
            for (int tb = 0; tb < 10; ++tb) nge += hist[tid * 10 + tb];  // v>=0 count
            unsigned rsu = srs[tid];
            unsigned nlt = (rsu >= nge) ? (rsu - nge) : 0u;              // v<0 count
            float hminp = fmaxf(mn, 0.f), denp = fmaxf(mx, 0.f) - hminp;
            float hminn = fminf(mn, 0.f), denn = fminf(mx, 0.f) - hminn;
            float la = (float)l;
            float tp0 = ((0.0f - hminp) / denp) * 9.0f;  // pos bin of clipped (v<0)
            float tn0 = ((0.0f - hminn) / denn) * 9.0f;  // neg bin of clipped (v>=0)
            int bp = (int)(la * 10.0f + tp0); bp = min(max(bp, 0), 2559);
            int bn = (int)(la * 10.0f + tn0); bn = min(max(bn, 0), 2559);
            if (nlt && bp >= g0off && bp < g0off + 640) atomicAdd(&hist[bp - g0off], nlt);
            if (nge && bn >= g0off && bn < g0off + 640) atomicAdd(&hist[640 + bn - g0off], nge);
        }
        __syncthreads();
        for (int i = tid; i < 1280; i += 256) {
            int pos = (i < 640);
            int rr = pos ? i : i - 640;
            int lseg = rr / 10, tb = rr % 10;
            int seg = l0 + lseg;
            int tt = base * 4 + (pos ? 0 : 2) + d;
            float rsf = (float)srs[lseg];
            out[TH_OFF + ((size_t)(bg * NSEG + seg) * 3 + c) * 80 + tt * 10 + tb] =
                (float)hist[i] / (24.0f * rsf);
        }
    } else {
        for (int seg = bx - 288; seg < 1536; seg += (gridDim.x - 288)) {
            int bg = seg >> 8;        // seg = bg*256 + s
            int s = seg & 255;
            if (tid < 76) {
                unsigned rs = 0;
                const unsigned* rp = rsp + (size_t)(bg * RSP) * NSEG + s;
                #pragma unroll 4
                for (int p = 0; p < RSP; ++p) rs += rp[(size_t)p * NSEG];
                float rsf = (float)rs;
                if (tid < 75) {
                    int c = tid / 25, cb = tid - c * 25;
                    float cd = 3.0f * rsf;
                    const unsigned* src = chp + ((size_t)((bg * 3 + c) * CHP)) * 6400 + s * 25 + cb;
                    unsigned sum = 0;
                    #pragma unroll 4
                    for (int p = 0; p < CHP; ++p) sum += src[(size_t)p * 6400];
                    out[CH_OFF + (size_t)seg * 75 + tid] = (float)sum / cd;
                } else {
                    out[seg] = rsf;
                    int xmn = INT_MAX, xmx = INT_MIN, ymn = INT_MAX, ymx = INT_MIN;
                    const int* p0 = bxmin + (size_t)(bg * RSP) * NSEG + s;
                    const int* p1 = bxmax + (size_t)(bg * RSP) * NSEG + s;
                    const int* p2 = bymin + (size_t)(bg * RSP) * NSEG + s;
                    const int* p3 = bymax + (size_t)(bg * RSP) * NSEG + s;
                    for (int p = 0; p < RSP; ++p) {
                        xmn = min(xmn, p0[(size_t)p * NSEG]); xmx = max(xmx, p1[(size_t)p * NSEG]);
                        ymn = min(ymn, p2[(size_t)p * NSEG]); ymx = max(ymx, p3[(size_t)p * NSEG]);
                    }
                    if (!(rsf > 0.f)) { xmn = IW; ymn = IW; xmx = 0; ymx = 0; }
                    float* xy = out + XY_OFF + (size_t)seg * 4;
                    xy[0] = (float)xmn; xy[1] = (float)ymn;
                    xy[2] = (float)(xmx - xmn); xy[3] = (float)(ymx - ymn);
                }
            }
        }
    }
}

extern "C" void kernel_launch(void* const* d_in, const int* in_sizes, int n_in,
                              void* d_out, int out_size, void* d_ws, size_t ws_size,
                              hipStream_t stream) {
    const float* img = (const float*)d_in[0];
    const int* lab = (const int*)d_in[1];
    float* out = (float*)d_out;

    float* gmaps = (float*)d_ws;                        // 24 maps * 262144 f32 (25.2 MB)
    float* pmin = gmaps + (size_t)24 * HW;              // 24*NBLK
    float* pmax = pmin + 24 * NBLK;
    unsigned* thp = (unsigned*)(pmax + 24 * NBLK);      // 72*THP*5120 u32 (~35.4 MB)
    unsigned* chp = thp + (size_t)72 * THP * 5120;      // 18*CHP*6400 u32 (~29.5 MB)
    unsigned char* lab8 = (unsigned char*)(chp + (size_t)18 * CHP * 6400);  // 6*HW u8
    unsigned* rsp = (unsigned*)(lab8 + (size_t)6 * HW); // 6*RSP*256 u32
    int* bxmin = (int*)(rsp + 6 * RSP * NSEG);
    int* bxmax = bxmin + 6 * RSP * NSEG;
    int* bymin = bxmax + 6 * RSP * NSEG;
    int* bymax = bymin + 6 * RSP * NSEG;

    hipLaunchKernelGGL(k_front, dim3(3072), dim3(256), 0, stream,
                       img, lab, gmaps, pmin, pmax, lab8, chp, rsp, bxmin, bxmax, bymin, bymax);
    hipLaunchKernelGGL(k_thist, dim3(THP, 72), dim3(256), 0, stream, gmaps, lab8, pmin, pmax, thp);
    hipLaunchKernelGGL(k_thfinal, dim3(288 + 256), dim3(256), 0, stream,
                       thp, chp, rsp, pmin, pmax, bxmin, bxmax, bymin, bymax, out);
}

// Round 6
// 125.663 us; speedup vs baseline: 1.9579x; 1.9579x over previous
//
#include <hip/hip_runtime.h>
#include <climits>

#define HW 262144          // 512*512
#define IW 512
#define RN 725             // virtual rotated canvas side
#define NSEG 256
#define CH_OFF 1536
#define TH_OFF 116736
#define XY_OFF 485376
#define NBLK 256           // grad tiles per plane; minmax partial count
#define THP 24             // pixel splits in thist role
#define CHP 32             // pixel splits in regchist role

// grad tile geometry (r16): output tile 64x16; rotated source box 24x72 at (-156,-156).
#define ASTR 67
#define RSTR 73
#define ROFF 156

static __device__ __forceinline__ float rtap_l(const float* __restrict__ Rt,
                                               int rx0, int ry0, int cx, int cy) {
    if (cx < 0 || cx >= RN || cy < 0 || cy >= RN) return 0.f;
    const float cs = 0.7071067811865476f;
    float xg = (float)cx - 362.0f;
    float yg = (float)cy - 362.0f;
    float xi = cs * xg - cs * yg + 255.5f;
    float yi = cs * xg + cs * yg + 255.5f;
    int xs = (int)rintf(xi);
    int ys = (int)rintf(yi);
    if (xs < 0 || xs >= IW || ys < 0 || ys >= IW) return 0.f;
    return Rt[(ys - ry0) * RSTR + (xs - rx0)];
}

// block-level min/max of map m's NBLK partials; all threads get (mn,mx)
static __device__ __forceinline__ void mm_of_map(const float* __restrict__ pmin,
                                                 const float* __restrict__ pmax,
                                                 int m, float* slo, float* shi,
                                                 float& mn, float& mx) {
    int tid = threadIdx.x;
    float lo = 3.4e38f, hi = -3.4e38f;
    for (int i = tid; i < NBLK; i += 256) {
        lo = fminf(lo, pmin[m * NBLK + i]);
        hi = fmaxf(hi, pmax[m * NBLK + i]);
    }
    slo[tid] = lo; shi[tid] = hi;
    __syncthreads();
    for (int off = 128; off > 0; off >>= 1) {
        if (tid < off) {
            slo[tid] = fminf(slo[tid], slo[tid + off]);
            shi[tid] = fmaxf(shi[tid], shi[tid + off]);
        }
        __syncthreads();
    }
    mn = slo[0]; mx = shi[0];
    __syncthreads();
}

// ---- K1: gradients (r4 verbatim) + min/max partials + init chores + u8 pack ----
__global__ __launch_bounds__(256) void k_grad(
    const float* __restrict__ img, const int* __restrict__ lab,
    float* __restrict__ gmaps,
    float* __restrict__ pmin, float* __restrict__ pmax,
    float* __restrict__ out, int* __restrict__ bbmin, int* __restrict__ bbmax,
    unsigned char* __restrict__ lab8)
{
    int t = blockIdx.x;        // tile index: tx0=(t&7)*64, ty0=(t>>3)*16
    int bc = blockIdx.y;
    int tid = threadIdx.x;
    // init chores for later-launched consumers (stream order covers visibility)
    if (bc == 0 && t < 6) {                     // zero rs: 6*256 == 1536
        out[t * 256 + tid] = 0.0f;
    } else if (bc == 1 && t < 12) {             // bbox init: 12*256 == 2*3072
        int i = t * 256 + tid;
        bbmin[i] = INT_MAX;
        bbmax[i] = INT_MIN;
    }
    // u8 label pack: 256 blocks * 256 thr * 4 labels == HW per plane
    {
        int i = t * 256 + tid;
        int4 l = ((const int4*)(lab + (size_t)bc * HW))[i];
        unsigned v = (unsigned)(l.x & 255) | ((unsigned)(l.y & 255) << 8) |
                     ((unsigned)(l.z & 255) << 16) | ((unsigned)(l.w & 255) << 24);
        ((unsigned*)(lab8 + (size_t)bc * HW))[i] = v;
    }
    __shared__ float At[18 * ASTR];
    __shared__ float Rt[24 * RSTR];
    __shared__ float slo[4][256], shi[4][256];
    int tx0 = (t & 7) << 6;
    int ty0 = (t >> 3) << 4;
    const float* im = img + (size_t)bc * HW;
    int lane = tid & 63, wr = tid >> 6;
    // stage direct tile: rows ty0-1..ty0+16 (18), cols tx0-1..tx0+64 (66)
    for (int r = wr; r < 18; r += 4) {
        int gy = ty0 - 1 + r;
        bool yok = (gy >= 0 && gy < IW);
        int gx = tx0 - 1 + lane;
        At[r * ASTR + lane] = (yok && gx >= 0 && gx < IW) ? im[gy * IW + gx] : 0.f;
        if (lane < 2) {
            int gx2 = gx + 64;
            At[r * ASTR + lane + 64] = (yok && gx2 >= 0 && gx2 < IW) ? im[gy * IW + gx2] : 0.f;
        }
    }
    // stage rot tile: rows ty0-156..ty0-133 (24), cols tx0-156..tx0-85 (72)
    for (int r = wr; r < 24; r += 4) {
        int gy = ty0 - ROFF + r;
        bool yok = (gy >= 0 && gy < IW);
        int gx = tx0 - ROFF + lane;
        Rt[r * RSTR + lane] = (yok && gx >= 0 && gx < IW) ? im[gy * IW + gx] : 0.f;
        if (lane < 8) {
            int gx2 = gx + 64;
            Rt[r * RSTR + lane + 64] = (yok && gx2 >= 0 && gx2 < IW) ? im[gy * IW + gx2] : 0.f;
        }
    }
    __syncthreads();
    const float cs = 0.7071067811865476f;  // cos(-45); sin(-45) = -cs
    int rx0 = tx0 - ROFF, ry0 = ty0 - ROFF;
    float mn0 = 3.4e38f, mx0 = -3.4e38f, mn1 = 3.4e38f, mx1 = -3.4e38f;
    float mn2 = 3.4e38f, mx2 = -3.4e38f, mn3 = 3.4e38f, mx3 = -3.4e38f;
    #pragma unroll
    for (int it = 0; it < 4; ++it) {
        int ly = wr * 4 + it;              // 0..15
        int x = tx0 + lane, y = ty0 + ly;
        int p = y * IW + x;
        const float* Ar = At + ly * ASTR + lane;
        float a  = Ar[0],            b2 = Ar[1],            c2 = Ar[2];
        float d2 = Ar[ASTR],                                 e2 = Ar[ASTR + 2];
        float f2 = Ar[2 * ASTR],     h2 = Ar[2 * ASTR + 1], i9 = Ar[2 * ASTR + 2];
        float g0 = -3.f*a + 3.f*c2 + 10.f*d2 + 10.f*e2 - 3.f*f2 + 3.f*i9;
        float g1 = -3.f*a + 10.f*b2 - 3.f*c2 + 3.f*f2 + 10.f*h2 + 3.f*i9;
        gmaps[((size_t)(bc*2+0))*HW + p] = g0;
        gmaps[((size_t)(bc*2+1))*HW + p] = g1;
        float xgc = (float)(x + 105) - 512.5f;
        float ygc = (float)(y + 105) - 512.5f;
        float t1 = cs * xgc, t2 = cs * ygc;
        float xi = (t1 + t2) + 362.0f;
        float yi = (-t1 + t2) + 362.0f;
        int xn = (int)rintf(xi);
        int yn = (int)rintf(yi);
        float r0 = 0.f, r1 = 0.f;
        if (xn >= 0 && xn < RN && yn >= 0 && yn < RN) {
            float ra = rtap_l(Rt, rx0, ry0, xn-1, yn-1);
            float rb = rtap_l(Rt, rx0, ry0, xn,   yn-1);
            float rc = rtap_l(Rt, rx0, ry0, xn+1, yn-1);
            float rd = rtap_l(Rt, rx0, ry0, xn-1, yn);
            float re = rtap_l(Rt, rx0, ry0, xn+1, yn);
            float rf = rtap_l(Rt, rx0, ry0, xn-1, yn+1);
            float rh = rtap_l(Rt, rx0, ry0, xn,   yn+1);
            float ri = rtap_l(Rt, rx0, ry0, xn+1, yn+1);
            r0 = -3.f*ra + 3.f*rc + 10.f*rd + 10.f*re - 3.f*rf + 3.f*ri;
            r1 = -3.f*ra + 10.f*rb - 3.f*rc + 3.f*rf + 10.f*rh + 3.f*ri;
        }
        gmaps[((size_t)(12 + bc*2+0))*HW + p] = r0;
        gmaps[((size_t)(12 + bc*2+1))*HW + p] = r1;
        mn0 = fminf(mn0, g0); mx0 = fmaxf(mx0, g0);
        mn1 = fminf(mn1, g1); mx1 = fmaxf(mx1, g1);
        mn2 = fminf(mn2, r0); mx2 = fmaxf(mx2, r0);
        mn3 = fminf(mn3, r1); mx3 = fmaxf(mx3, r1);
    }
    slo[0][tid] = mn0; shi[0][tid] = mx0;
    slo[1][tid] = mn1; shi[1][tid] = mx1;
    slo[2][tid] = mn2; shi[2][tid] = mx2;
    slo[3][tid] = mn3; shi[3][tid] = mx3;
    __syncthreads();
    for (int off = 128; off > 0; off >>= 1) {
        if (tid < off) {
            #pragma unroll
            for (int k = 0; k < 4; ++k) {
                slo[k][tid] = fminf(slo[k][tid], slo[k][tid + off]);
                shi[k][tid] = fmaxf(shi[k][tid], shi[k][tid + off]);
            }
        }
        __syncthreads();
    }
    if (tid < 4) {
        int m = (tid < 2) ? (bc*2 + tid) : (12 + bc*2 + (tid - 2));
        pmin[m * NBLK + t] = slo[tid][0];
        pmax[m * NBLK + t] = shi[tid][0];
    }
}

// ==== K2 (r20): thist (1728) || regchist (576), role-interleaved 3:1 ====
// Both roles depend only on K1 and are mutually independent. Union LDS =
// thist's 22.5KB -> 7 blocks/CU for BOTH roles (r3/r5 merges failed by
// growing LDS; this one doesn't). regchist color hist is u16-PACKED
// (two bins/word, atomicAdd(1<<16*half); max count/block 8192 < 2^15 so
// no cross-half carry -> bit-exact) to fit 17.4KB under the union.
// rs/bbox keep the r4-proven global-atomic flush (init chores in K1).
__global__ __launch_bounds__(256) void k_hist(
    const float* __restrict__ maps, const float* __restrict__ img,
    const unsigned char* __restrict__ lab8,
    const float* __restrict__ pmin, const float* __restrict__ pmax,
    unsigned* __restrict__ thp, unsigned* __restrict__ chp,
    float* __restrict__ rs_out, int* __restrict__ bbmin, int* __restrict__ bbmax)
{
    __shared__ __align__(16) unsigned char smem[23040];
    int bxid = blockIdx.x;
    int tid = threadIdx.x;
    if ((bxid & 3) != 3) {
        // ---- thist role (r4 verbatim body): idx in [0,1728) ----
        int idx = bxid - (bxid >> 2);
        int gy = idx / THP;            // [0,72): (r*3 + gi)
        int split = idx - gy * THP;    // [0,THP)
        unsigned* cnt = (unsigned*)smem;            // 5120 u32 = 20480 B
        float* slo = (float*)(smem + 20480);        // 256 f
        float* shi = slo + 256;                     // 256 f
        int gi = gy % 3;
        int r = gy / 3;
        int base = r & 1;
        int bd = r >> 1;
        int d = bd & 1;
        int bc = bd >> 1;
        int b = bc / 3;
        int m = base * 12 + bc * 2 + d;
        float mn, mx;
        mm_of_map(pmin, pmax, m, slo, shi, mn, mx);
        for (int i = tid; i < 5120; i += 256) cnt[i] = 0;
        __syncthreads();
        float hminp = fmaxf(mn, 0.f), denp = fmaxf(mx, 0.f) - hminp;
        float hminn = fminf(mn, 0.f), denn = fminf(mx, 0.f) - hminn;
        const float4* src = (const float4*)(maps + (size_t)m * HW);
        const unsigned* lp = (const unsigned*)(lab8 + (size_t)(b * 3 + gi) * HW);
        for (int i = split * 256 + tid; i < HW / 4; i += 256 * THP) {
            float4 v4 = src[i];
            unsigned l4 = lp[i];
#define TH1(V, SH)                                                     \
            {                                                          \
                float v = (V);                                         \
                bool ge = (v >= 0.f);                                  \
                float hm = ge ? hminp : hminn;                         \
                float dn = ge ? denp : denn;                           \
                float t9 = ((v - hm) / dn) * 9.0f;                     \
                int bi = (int)((float)((l4 >> SH) & 255u) * 10.0f + t9); \
                bi = min(max(bi, 0), 2559);                            \
                atomicAdd(&cnt[(ge ? 0 : 2560) + bi], 1u);             \
            }
            TH1(v4.x, 0) TH1(v4.y, 8) TH1(v4.z, 16) TH1(v4.w, 24)
#undef TH1
        }
        __syncthreads();
        unsigned* dst = thp + ((size_t)(gy * THP + split)) * 5120;
        for (int i = tid; i < 5120; i += 256) dst[i] = cnt[i];
    } else {
        // ---- regchist role: w in [0,576): row gy=w>>5, split sp=w&31 ----
        int w = bxid >> 2;
        int gy = w >> 5;           // (b*3+g)*3 + c
        int sp = w & 31;
        int c = gy % 3;
        int bg = gy / 3;
        int b = bg / 3;
        unsigned* pk = (unsigned*)smem;             // 3200 words (6400 u16 bins)
        unsigned* prc = pk + 3200;                  // 128 words (256 u16 rcnt)
        int* sxmin = (int*)(prc + 128);             // 4x256 int (17408 B total)
        int* sxmax = sxmin + NSEG;
        int* symin = sxmax + NSEG;
        int* symax = symin + NSEG;
        bool do_reg = (c == 0);
        for (int i = tid; i < 3200; i += 256) pk[i] = 0;
        if (do_reg) {
            if (tid < 128) prc[tid] = 0;
            sxmin[tid] = INT_MAX; sxmax[tid] = INT_MIN;
            symin[tid] = INT_MAX; symax[tid] = INT_MIN;
        }
        __syncthreads();
        const float4* ip = (const float4*)(img + ((size_t)b * 3 + c) * HW);
        const unsigned* lp = (const unsigned*)(lab8 + (size_t)bg * HW);
        for (int i = sp * 256 + tid; i < HW / 4; i += 256 * CHP) {
            float4 v4 = ip[i];
            unsigned l4 = lp[i];
            int l0 = l4 & 255, l1 = (l4 >> 8) & 255, l2 = (l4 >> 16) & 255, l3 = l4 >> 24;
            int b0 = (int)((float)l0 * 25.0f + v4.x * 24.0f);
            int b1 = (int)((float)l1 * 25.0f + v4.y * 24.0f);
            int b2 = (int)((float)l2 * 25.0f + v4.z * 24.0f);
            int b3 = (int)((float)l3 * 25.0f + v4.w * 24.0f);
            b0 = min(max(b0, 0), 6399); b1 = min(max(b1, 0), 6399);
            b2 = min(max(b2, 0), 6399); b3 = min(max(b3, 0), 6399);
            atomicAdd(&pk[b0 >> 1], 1u << ((b0 & 1) << 4));
            atomicAdd(&pk[b1 >> 1], 1u << ((b1 & 1) << 4));
            atomicAdd(&pk[b2 >> 1], 1u << ((b2 & 1) << 4));
            atomicAdd(&pk[b3 >> 1], 1u << ((b3 & 1) << 4));
            if (do_reg) {
                int p = i << 2;
                int y = p >> 9, x = p & 511;
                atomicAdd(&prc[l0 >> 1], 1u << ((l0 & 1) << 4));
                atomicAdd(&prc[l1 >> 1], 1u << ((l1 & 1) << 4));
                atomicAdd(&prc[l2 >> 1], 1u << ((l2 & 1) << 4));
                atomicAdd(&prc[l3 >> 1], 1u << ((l3 & 1) << 4));
                atomicMin(&sxmin[l0], x);     atomicMax(&sxmax[l0], x);
                atomicMin(&sxmin[l1], x + 1); atomicMax(&sxmax[l1], x + 1);
                atomicMin(&sxmin[l2], x + 2); atomicMax(&sxmax[l2], x + 2);
                atomicMin(&sxmin[l3], x + 3); atomicMax(&sxmax[l3], x + 3);
                atomicMin(&symin[l0], y); atomicMax(&symax[l0], y);
                atomicMin(&symin[l1], y); atomicMax(&symax[l1], y);
                atomicMin(&symin[l2], y); atomicMax(&symax[l2], y);
                atomicMin(&symin[l3], y); atomicMax(&symax[l3], y);
            }
        }
        __syncthreads();
        // coalesced partial store (unpack halves): zero global atomics for ch
        unsigned* dst = chp + ((size_t)gy * CHP + sp) * 6400;
        for (int i = tid; i < 6400; i += 256)
            dst[i] = (pk[i >> 1] >> ((i & 1) << 4)) & 0xFFFFu;
        if (do_reg) {
            unsigned rc = (prc[tid >> 1] >> ((tid & 1) << 4)) & 0xFFFFu;
            if (rc) atomicAdd(&rs_out[bg * NSEG + tid], (float)rc);
            if (sxmin[tid] != INT_MAX) {
                atomicMin(&bbmin[bg * NSEG + tid], sxmin[tid]);
                atomicMax(&bbmax[bg * NSEG + tid], sxmax[tid]);
                atomicMin(&bbmin[1536 + bg * NSEG + tid], symin[tid]);
                atomicMax(&bbmax[1536 + bg * NSEG + tid], symax[tid]);
            }
        }
    }
}

// ---- K3: th chunked-reduce + sign-completion + normalize (bx<288);
//      ch single-seg blocks: partial-reduce + normalize + xywh (r20: 1536 blocks,
//      one seg each — r4 math verbatim, just 6x the parallelism) ----
__global__ __launch_bounds__(256) void k_thfinal(
    const unsigned* __restrict__ thp, const unsigned* __restrict__ chp,
    const float* __restrict__ pmin, const float* __restrict__ pmax,
    const int* __restrict__ bbmin, const int* __restrict__ bbmax,
    float* __restrict__ out)
{
    int tid = threadIdx.x;
    int bx = blockIdx.x;
    if (bx < 288) {
        __shared__ unsigned hist[1280];    // [0,640) pos, [640,1280) neg, 64 labels
        __shared__ float slo[256], shi[256];
        int gy = bx >> 2;
        int ck = bx & 3;
        int l0 = ck << 6;                  // first label of chunk
        int gi = gy % 3; int r = gy / 3; int base = r & 1;
        int bd = r >> 1; int d = bd & 1; int bc = bd >> 1;
        int b = bc / 3, c = bc - b * 3;
        int m = base * 12 + bc * 2 + d;
        float mn, mx;
        mm_of_map(pmin, pmax, m, slo, shi, mn, mx);
        int g0off = l0 * 10;
        for (int i = tid; i < 1280; i += 256) {
            int g = (i < 640) ? (g0off + i) : (2560 + g0off + (i - 640));
            unsigned s = 0;
            #pragma unroll 4
            for (int p = 0; p < THP; ++p) s += thp[((size_t)(gy * THP + p)) * 5120 + g];
            hist[i] = s;
        }
        __syncthreads();
        if (tid < 64) {
            int l = l0 + tid;   // this chunk's labels: sign-completion
            unsigned nge = 0;
            for (int tb = 0; tb < 10; ++tb) nge += hist[tid * 10 + tb];  // v>=0 count
            float rsf = out[(b * 3 + gi) * NSEG + l];
            unsigned rsu = (unsigned)rsf;
            unsigned nlt = (rsu >= nge) ? (rsu - nge) : 0u;              // v<0 count
            float hminp = fmaxf(mn, 0.f), denp = fmaxf(mx, 0.f) - hminp;
            float hminn = fminf(mn, 0.f), denn = fminf(mx, 0.f) - hminn;
            float la = (float)l;
            float tp0 = ((0.0f - hminp) / denp) * 9.0f;  // pos bin of clipped (v<0)
            float tn0 = ((0.0f - hminn) / denn) * 9.0f;  // neg bin of clipped (v>=0)
            int bp = (int)(la * 10.0f + tp0); bp = min(max(bp, 0), 2559);
            int bn = (int)(la * 10.0f + tn0); bn = min(max(bn, 0), 2559);
            if (nlt && bp >= g0off && bp < g0off + 640) atomicAdd(&hist[bp - g0off], nlt);
            if (nge && bn >= g0off && bn < g0off + 640) atomicAdd(&hist[640 + bn - g0off], nge);
        }
        __syncthreads();
        for (int i = tid; i < 1280; i += 256) {
            int pos = (i < 640);
            int rr = pos ? i : i - 640;
            int lseg = rr / 10, tb = rr % 10;
            int seg = l0 + lseg;
            int tt = base * 4 + (pos ? 0 : 2) + d;
            float rsf = out[(b * 3 + gi) * NSEG + seg];
            out[TH_OFF + ((size_t)((b * 3 + gi) * NSEG + seg) * 3 + c) * 80 + tt * 10 + tb] =
                (float)hist[i] / (24.0f * rsf);
        }
    } else {
        int seg = bx - 288;                // [0,1536): one seg per block
        int bg = seg >> 8;
        int s = seg & 255;
        float rsf = out[seg];
        float cd = 3.0f * rsf;
        float* ch = out + CH_OFF + (size_t)seg * 75;
        if (tid < 75) {
            int c = tid / 25, cb = tid - c * 25;
            unsigned sum = 0;
            const unsigned* src = chp + ((size_t)(bg * 3 + c) * CHP) * 6400 + s * 25 + cb;
            #pragma unroll 4
            for (int p = 0; p < CHP; ++p) sum += src[(size_t)p * 6400];
            ch[tid] = (float)sum / cd;
        } else if (tid == 75) {
            int xmin, xmax, ymin, ymax;
            if (rsf > 0.f) {
                xmin = bbmin[seg]; ymin = bbmin[1536 + seg];
                xmax = bbmax[seg]; ymax = bbmax[1536 + seg];
            } else {
                xmin = IW; ymin = IW; xmax = 0; ymax = 0;
            }
            float* xy = out + XY_OFF + (size_t)seg * 4;
            xy[0] = (float)xmin; xy[1] = (float)ymin;
            xy[2] = (float)(xmax - xmin); xy[3] = (float)(ymax - ymin);
        }
    }
}

extern "C" void kernel_launch(void* const* d_in, const int* in_sizes, int n_in,
                              void* d_out, int out_size, void* d_ws, size_t ws_size,
                              hipStream_t stream) {
    const float* img = (const float*)d_in[0];
    const int* lab = (const int*)d_in[1];
    float* out = (float*)d_out;

    float* gmaps = (float*)d_ws;                        // 24 maps * 262144 f32 (25.2 MB)
    float* pmin = gmaps + (size_t)24 * HW;              // 24*NBLK
    float* pmax = pmin + 24 * NBLK;
    int* bbmin = (int*)(pmax + 24 * NBLK);              // 3072: [xmin(1536), ymin(1536)]
    int* bbmax = bbmin + 3072;                          // 3072: [xmax(1536), ymax(1536)]
    unsigned* thp = (unsigned*)(bbmax + 3072);          // 72*THP*5120 u32 (~35.4 MB)
    unsigned* chp = thp + (size_t)72 * THP * 5120;      // 18*CHP*6400 u32 (~14.7 MB)
    unsigned char* lab8 = (unsigned char*)(chp + (size_t)18 * CHP * 6400);  // 6*HW u8

    hipLaunchKernelGGL(k_grad, dim3(NBLK, 6), dim3(256), 0, stream,
                       img, lab, gmaps, pmin, pmax, out, bbmin, bbmax, lab8);
    hipLaunchKernelGGL(k_hist, dim3(2304), dim3(256), 0, stream,
                       gmaps, img, lab8, pmin, pmax, thp, chp, out, bbmin, bbmax);
    hipLaunchKernelGGL(k_thfinal, dim3(288 + 1536), dim3(256), 0, stream,
                       thp, chp, pmin, pmax, bbmin, bbmax, out);
}

// Round 7
// 119.924 us; speedup vs baseline: 2.0516x; 1.0479x over previous
//
#include <hip/hip_runtime.h>
#include <climits>

#define HW 262144          // 512*512
#define IW 512
#define RN 725             // virtual rotated canvas side
#define NSEG 256
#define CH_OFF 1536
#define TH_OFF 116736
#define XY_OFF 485376
#define NBLK 256           // grad tiles per plane; minmax partial count
#define THP 24             // pixel splits in thist
#define CHP 32             // pixel splits in regchist role

// grad tile geometry (r16): output tile 64x16; rotated source box 24x72 at (-156,-156).
#define ASTR 67
#define RSTR 73
#define ROFF 156

static __device__ __forceinline__ float rtap_l(const float* __restrict__ Rt,
                                               int rx0, int ry0, int cx, int cy) {
    if (cx < 0 || cx >= RN || cy < 0 || cy >= RN) return 0.f;
    const float cs = 0.7071067811865476f;
    float xg = (float)cx - 362.0f;
    float yg = (float)cy - 362.0f;
    float xi = cs * xg - cs * yg + 255.5f;
    float yi = cs * xg + cs * yg + 255.5f;
    int xs = (int)rintf(xi);
    int ys = (int)rintf(yi);
    if (xs < 0 || xs >= IW || ys < 0 || ys >= IW) return 0.f;
    return Rt[(ys - ry0) * RSTR + (xs - rx0)];
}

// block-level min/max of map m's NBLK partials; all threads get (mn,mx)
static __device__ __forceinline__ void mm_of_map(const float* __restrict__ pmin,
                                                 const float* __restrict__ pmax,
                                                 int m, float* slo, float* shi,
                                                 float& mn, float& mx) {
    int tid = threadIdx.x;
    float lo = 3.4e38f, hi = -3.4e38f;
    for (int i = tid; i < NBLK; i += 256) {
        lo = fminf(lo, pmin[m * NBLK + i]);
        hi = fmaxf(hi, pmax[m * NBLK + i]);
    }
    slo[tid] = lo; shi[tid] = hi;
    __syncthreads();
    for (int off = 128; off > 0; off >>= 1) {
        if (tid < off) {
            slo[tid] = fminf(slo[tid], slo[tid + off]);
            shi[tid] = fmaxf(shi[tid], shi[tid + off]);
        }
        __syncthreads();
    }
    mn = slo[0]; mx = shi[0];
    __syncthreads();
}

// ==== K1 (r21): grad (1536) || packed-regchist (576), 8:3 mod-11 interleave ====
// regchist reads int32 lab (independent of grad's lab8 pack — no intra-kernel
// race); rs/bbox are deterministic per-block partials (r5's failure was the
// SERIAL reduce in thfinal, fixed in K3 — partials themselves are fine).
// LDS union = 20KB (grad) vs 17.4KB (packed regchist) -> 8 blocks/CU, same
// as grad standalone (r3's 30.7KB mistake avoided). No global atomics,
// no init chores anywhere.
__global__ __launch_bounds__(256) void k_front(
    const float* __restrict__ img, const int* __restrict__ lab,
    float* __restrict__ gmaps, float* __restrict__ pmin, float* __restrict__ pmax,
    unsigned char* __restrict__ lab8, unsigned* __restrict__ chp_w,
    unsigned* __restrict__ rsp, int* __restrict__ bxmin, int* __restrict__ bxmax,
    int* __restrict__ bymin, int* __restrict__ bymax)
{
    __shared__ __align__(16) unsigned char smem[20480];
    int bxid = blockIdx.x;
    int tid = threadIdx.x;
    int grp = bxid / 11, rem = bxid % 11;   // 2112 = 192*11
    if (rem < 8) {
        // ---- grad role: u in [0,1536): tile (u&255), plane bc=(u>>8) ----
        int u = grp * 8 + rem;
        int tile = u & 255;
        int bc = u >> 8;
        float* At = (float*)smem;                               // 1206 f
        float* Rt = At + 18 * ASTR;                             // 1752 f
        float (*slo)[256] = (float (*)[256])(Rt + 24 * RSTR);   // 4*256 f
        float (*shi)[256] = slo + 4;                            // 4*256 f (20024 B)
        // u8 label pack for k_thist: 256 blocks/plane * 256 thr * 4 == HW
        {
            int i = tile * 256 + tid;
            int4 l = ((const int4*)(lab + (size_t)bc * HW))[i];
            unsigned v = (unsigned)(l.x & 255) | ((unsigned)(l.y & 255) << 8) |
                         ((unsigned)(l.z & 255) << 16) | ((unsigned)(l.w & 255) << 24);
            ((unsigned*)(lab8 + (size_t)bc * HW))[i] = v;
        }
        int tx0 = (tile & 7) << 6;
        int ty0 = (tile >> 3) << 4;
        const float* im = img + (size_t)bc * HW;
        int lane = tid & 63, wr = tid >> 6;
        for (int r = wr; r < 18; r += 4) {
            int gy = ty0 - 1 + r;
            bool yok = (gy >= 0 && gy < IW);
            int gx = tx0 - 1 + lane;
            At[r * ASTR + lane] = (yok && gx >= 0 && gx < IW) ? im[gy * IW + gx] : 0.f;
            if (lane < 2) {
                int gx2 = gx + 64;
                At[r * ASTR + lane + 64] = (yok && gx2 >= 0 && gx2 < IW) ? im[gy * IW + gx2] : 0.f;
            }
        }
        for (int r = wr; r < 24; r += 4) {
            int gy = ty0 - ROFF + r;
            bool yok = (gy >= 0 && gy < IW);
            int gx = tx0 - ROFF + lane;
            Rt[r * RSTR + lane] = (yok && gx >= 0 && gx < IW) ? im[gy * IW + gx] : 0.f;
            if (lane < 8) {
                int gx2 = gx + 64;
                Rt[r * RSTR + lane + 64] = (yok && gx2 >= 0 && gx2 < IW) ? im[gy * IW + gx2] : 0.f;
            }
        }
        __syncthreads();
        const float cs = 0.7071067811865476f;
        int rx0 = tx0 - ROFF, ry0 = ty0 - ROFF;
        float mn0 = 3.4e38f, mx0 = -3.4e38f, mn1 = 3.4e38f, mx1 = -3.4e38f;
        float mn2 = 3.4e38f, mx2 = -3.4e38f, mn3 = 3.4e38f, mx3 = -3.4e38f;
        #pragma unroll
        for (int it = 0; it < 4; ++it) {
            int ly = wr * 4 + it;
            int x = tx0 + lane, y = ty0 + ly;
            int p = y * IW + x;
            const float* Ar = At + ly * ASTR + lane;
            float a  = Ar[0],            b2 = Ar[1],            c2 = Ar[2];
            float d2 = Ar[ASTR],                                 e2 = Ar[ASTR + 2];
            float f2 = Ar[2 * ASTR],     h2 = Ar[2 * ASTR + 1], i9 = Ar[2 * ASTR + 2];
            float g0 = -3.f*a + 3.f*c2 + 10.f*d2 + 10.f*e2 - 3.f*f2 + 3.f*i9;
            float g1 = -3.f*a + 10.f*b2 - 3.f*c2 + 3.f*f2 + 10.f*h2 + 3.f*i9;
            gmaps[((size_t)(bc*2+0))*HW + p] = g0;
            gmaps[((size_t)(bc*2+1))*HW + p] = g1;
            float xgc = (float)(x + 105) - 512.5f;
            float ygc = (float)(y + 105) - 512.5f;
            float t1 = cs * xgc, t2 = cs * ygc;
            float xi = (t1 + t2) + 362.0f;
            float yi = (-t1 + t2) + 362.0f;
            int xn = (int)rintf(xi);
            int yn = (int)rintf(yi);
            float r0 = 0.f, r1 = 0.f;
            if (xn >= 0 && xn < RN && yn >= 0 && yn < RN) {
                float ra = rtap_l(Rt, rx0, ry0, xn-1, yn-1);
                float rb = rtap_l(Rt, rx0, ry0, xn,   yn-1);
                float rc = rtap_l(Rt, rx0, ry0, xn+1, yn-1);
                float rd = rtap_l(Rt, rx0, ry0, xn-1, yn);
                float re = rtap_l(Rt, rx0, ry0, xn+1, yn);
                float rf = rtap_l(Rt, rx0, ry0, xn-1, yn+1);
                float rh = rtap_l(Rt, rx0, ry0, xn,   yn+1);
                float ri = rtap_l(Rt, rx0, ry0, xn+1, yn+1);
                r0 = -3.f*ra + 3.f*rc + 10.f*rd + 10.f*re - 3.f*rf + 3.f*ri;
                r1 = -3.f*ra + 10.f*rb - 3.f*rc + 3.f*rf + 10.f*rh + 3.f*ri;
            }
            gmaps[((size_t)(12 + bc*2+0))*HW + p] = r0;
            gmaps[((size_t)(12 + bc*2+1))*HW + p] = r1;
            mn0 = fminf(mn0, g0); mx0 = fmaxf(mx0, g0);
            mn1 = fminf(mn1, g1); mx1 = fmaxf(mx1, g1);
            mn2 = fminf(mn2, r0); mx2 = fmaxf(mx2, r0);
            mn3 = fminf(mn3, r1); mx3 = fmaxf(mx3, r1);
        }
        slo[0][tid] = mn0; shi[0][tid] = mx0;
        slo[1][tid] = mn1; shi[1][tid] = mx1;
        slo[2][tid] = mn2; shi[2][tid] = mx2;
        slo[3][tid] = mn3; shi[3][tid] = mx3;
        __syncthreads();
        for (int off = 128; off > 0; off >>= 1) {
            if (tid < off) {
                #pragma unroll
                for (int k = 0; k < 4; ++k) {
                    slo[k][tid] = fminf(slo[k][tid], slo[k][tid + off]);
                    shi[k][tid] = fmaxf(shi[k][tid], shi[k][tid + off]);
                }
            }
            __syncthreads();
        }
        if (tid < 4) {
            int m = (tid < 2) ? (bc*2 + tid) : (12 + bc*2 + (tid - 2));
            pmin[m * NBLK + tile] = slo[tid][0];
            pmax[m * NBLK + tile] = shi[tid][0];
        }
    } else {
        // ---- packed regchist role: w in [0,576): row gy=w>>5, split sp=w&31 ----
        int w = grp * 3 + (rem - 8);
        int gy = w >> 5;           // (b*3+g)*3 + c
        int sp = w & 31;
        int c = gy % 3;
        int bg = gy / 3;
        int b = bg / 3;
        unsigned* pk = (unsigned*)smem;             // 3200 words (6400 u16 bins)
        unsigned* prc = pk + 3200;                  // 128 words (256 u16 rcnt)
        int* sxmin = (int*)(prc + 128);             // 4x256 int (17408 B total)
        int* sxmax = sxmin + NSEG;
        int* symin = sxmax + NSEG;
        int* symax = symin + NSEG;
        bool do_reg = (c == 0);
        for (int i = tid; i < 3200; i += 256) pk[i] = 0;
        if (do_reg) {
            if (tid < 128) prc[tid] = 0;
            sxmin[tid] = INT_MAX; sxmax[tid] = INT_MIN;
            symin[tid] = INT_MAX; symax[tid] = INT_MIN;
        }
        __syncthreads();
        const float4* ip = (const float4*)(img + ((size_t)b * 3 + c) * HW);
        const int4* lp = (const int4*)(lab + (size_t)bg * HW);
        for (int i = sp * 256 + tid; i < HW / 4; i += 256 * CHP) {
            float4 v4 = ip[i];
            int4 l4 = lp[i];
            int l0 = l4.x & 255, l1 = l4.y & 255, l2 = l4.z & 255, l3 = l4.w & 255;
            int b0 = (int)((float)l0 * 25.0f + v4.x * 24.0f);
            int b1 = (int)((float)l1 * 25.0f + v4.y * 24.0f);
            int b2 = (int)((float)l2 * 25.0f + v4.z * 24.0f);
            int b3 = (int)((float)l3 * 25.0f + v4.w * 24.0f);
            b0 = min(max(b0, 0), 6399); b1 = min(max(b1, 0), 6399);
            b2 = min(max(b2, 0), 6399); b3 = min(max(b3, 0), 6399);
            atomicAdd(&pk[b0 >> 1], 1u << ((b0 & 1) << 4));
            atomicAdd(&pk[b1 >> 1], 1u << ((b1 & 1) << 4));
            atomicAdd(&pk[b2 >> 1], 1u << ((b2 & 1) << 4));
            atomicAdd(&pk[b3 >> 1], 1u << ((b3 & 1) << 4));
            if (do_reg) {
                int p = i << 2;
                int y = p >> 9, x = p & 511;
                atomicAdd(&prc[l0 >> 1], 1u << ((l0 & 1) << 4));
                atomicAdd(&prc[l1 >> 1], 1u << ((l1 & 1) << 4));
                atomicAdd(&prc[l2 >> 1], 1u << ((l2 & 1) << 4));
                atomicAdd(&prc[l3 >> 1], 1u << ((l3 & 1) << 4));
                atomicMin(&sxmin[l0], x);     atomicMax(&sxmax[l0], x);
                atomicMin(&sxmin[l1], x + 1); atomicMax(&sxmax[l1], x + 1);
                atomicMin(&sxmin[l2], x + 2); atomicMax(&sxmax[l2], x + 2);
                atomicMin(&sxmin[l3], x + 3); atomicMax(&sxmax[l3], x + 3);
                atomicMin(&symin[l0], y); atomicMax(&symax[l0], y);
                atomicMin(&symin[l1], y); atomicMax(&symax[l1], y);
                atomicMin(&symin[l2], y); atomicMax(&symax[l2], y);
                atomicMin(&symin[l3], y); atomicMax(&symax[l3], y);
            }
        }
        __syncthreads();
        // store packed words directly (r21): chp stays u16 end-to-end
        unsigned* dst = chp_w + ((size_t)gy * CHP + sp) * 3200;
        for (int i = tid; i < 3200; i += 256) dst[i] = pk[i];
        if (do_reg) {
            size_t pi = (size_t)(bg * CHP + sp) * NSEG + tid;
            rsp[pi] = (prc[tid >> 1] >> ((tid & 1) << 4)) & 0xFFFFu;
            bxmin[pi] = sxmin[tid]; bxmax[pi] = sxmax[tid];
            bymin[pi] = symin[tid]; bymax[pi] = symax[tid];
        }
    }
}

// ---- K2: texture histogram (r18 body), u16-packed store (r21) ----
// Max count per bin per split-block = HW/THP = 10923 < 2^16 -> bit-exact pack.
// thp traffic halves: 35.4 -> 17.7 MB each way.
__global__ __launch_bounds__(256) void k_thist(
    const float* __restrict__ maps, const unsigned char* __restrict__ lab8,
    const float* __restrict__ pmin, const float* __restrict__ pmax,
    unsigned* __restrict__ thp_w)
{
    __shared__ unsigned cnt[5120];     // [0,2560) pos bins, [2560,5120) neg
    __shared__ float slo[256], shi[256];
    int gy = blockIdx.y;               // [0,72): (r*3 + gi)
    int split = blockIdx.x;            // [0,THP)
    int gi = gy % 3;
    int r = gy / 3;
    int base = r & 1;
    int bd = r >> 1;
    int d = bd & 1;
    int bc = bd >> 1;
    int b = bc / 3;
    int m = base * 12 + bc * 2 + d;
    float mn, mx;
    mm_of_map(pmin, pmax, m, slo, shi, mn, mx);
    for (int i = threadIdx.x; i < 5120; i += 256) cnt[i] = 0;
    __syncthreads();
    float hminp = fmaxf(mn, 0.f), denp = fmaxf(mx, 0.f) - hminp;
    float hminn = fminf(mn, 0.f), denn = fminf(mx, 0.f) - hminn;
    const float4* src = (const float4*)(maps + (size_t)m * HW);
    const unsigned* lp = (const unsigned*)(lab8 + (size_t)(b * 3 + gi) * HW);
    for (int i = split * 256 + threadIdx.x; i < HW / 4; i += 256 * THP) {
        float4 v4 = src[i];
        unsigned l4 = lp[i];
#define TH1(V, SH)                                                     \
        {                                                              \
            float v = (V);                                             \
            bool ge = (v >= 0.f);                                      \
            float hm = ge ? hminp : hminn;                             \
            float dn = ge ? denp : denn;                               \
            float t9 = ((v - hm) / dn) * 9.0f;                         \
            int bi = (int)((float)((l4 >> SH) & 255u) * 10.0f + t9);   \
            bi = min(max(bi, 0), 2559);                                \
            atomicAdd(&cnt[(ge ? 0 : 2560) + bi], 1u);                 \
        }
        TH1(v4.x, 0) TH1(v4.y, 8) TH1(v4.z, 16) TH1(v4.w, 24)
#undef TH1
    }
    __syncthreads();
    unsigned* dst = thp_w + ((size_t)(gy * THP + split)) * 2560;
    for (int i = threadIdx.x; i < 2560; i += 256)
        dst[i] = cnt[2 * i] | (cnt[2 * i + 1] << 16);
}

// ---- K3: th chunked-reduce (unpack u16) + sign-completion + normalize (bx<288);
//      ch single-seg blocks: PARALLEL partial reduce + normalize + rs + xywh.
//      r21: all rs/bbox come from partials, reduced thread-parallel (r5's
//      serial-walk failure mode eliminated). ----
__global__ __launch_bounds__(256) void k_final(
    const unsigned* __restrict__ thp_w, const unsigned* __restrict__ chp_w,
    const unsigned* __restrict__ rsp,
    const int* __restrict__ bxmin, const int* __restrict__ bxmax,
    const int* __restrict__ bymin, const int* __restrict__ bymax,
    const float* __restrict__ pmin, const float* __restrict__ pmax,
    float* __restrict__ out)
{
    int tid = threadIdx.x;
    int bx = blockIdx.x;
    if (bx < 288) {
        __shared__ unsigned hist[1280];    // [0,640) pos, [640,1280) neg, 64 labels
        __shared__ unsigned srs[64];
        __shared__ float slo[256], shi[256];
        int gy = bx >> 2;
        int ck = bx & 3;
        int l0 = ck << 6;                  // first label of chunk
        int gi = gy % 3; int r = gy / 3; int base = r & 1;
        int bd = r >> 1; int d = bd & 1; int bc = bd >> 1;
        int b = bc / 3, c = bc - b * 3;
        int m = base * 12 + bc * 2 + d;
        int bg = b * 3 + gi;
        float mn, mx;
        mm_of_map(pmin, pmax, m, slo, shi, mn, mx);
        // reduce packed partials: word w covers bins (2w,2w+1) of this chunk
        for (int w = tid; w < 640; w += 256) {
            int gw = (w < 320) ? (l0 * 5 + w) : (1280 + l0 * 5 + (w - 320));
            unsigned s0 = 0, s1 = 0;
            #pragma unroll 4
            for (int p = 0; p < THP; ++p) {
                unsigned v = thp_w[((size_t)(gy * THP + p)) * 2560 + gw];
                s0 += v & 0xFFFFu; s1 += v >> 16;
            }
            int bi = (w < 320) ? (2 * w) : (640 + 2 * (w - 320));
            hist[bi] = s0; hist[bi + 1] = s1;
        }
        if (tid < 64) {
            unsigned s = 0;
            #pragma unroll 4
            for (int p = 0; p < CHP; ++p) s += rsp[((size_t)(bg * CHP + p)) * NSEG + l0 + tid];
            srs[tid] = s;
        }
        __syncthreads();
        if (tid < 64) {
            int l = l0 + tid;   // this chunk's labels: sign-completion
            unsigned nge = 0;
            for (int tb = 0; tb < 10; ++tb) nge += hist[tid * 10 + tb];  // v>=0 count
            unsigned rsu = srs[tid];
            unsigned nlt = (rsu >= nge) ? (rsu - nge) : 0u;              // v<0 count
            float hminp = fmaxf(mn, 0.f), denp = fmaxf(mx, 0.f) - hminp;
            float hminn = fminf(mn, 0.f), denn = fminf(mx, 0.f) - hminn;
            float la = (float)l;
            float tp0 = ((0.0f - hminp) / denp) * 9.0f;  // pos bin of clipped (v<0)
            float tn0 = ((0.0f - hminn) / denn) * 9.0f;  // neg bin of clipped (v>=0)
            int g0off = l0 * 10;
            int bp = (int)(la * 10.0f + tp0); bp = min(max(bp, 0), 2559);
            int bn = (int)(la * 10.0f + tn0); bn = min(max(bn, 0), 2559);
            if (nlt && bp >= g0off && bp < g0off + 640) atomicAdd(&hist[bp - g0off], nlt);
            if (nge && bn >= g0off && bn < g0off + 640) atomicAdd(&hist[640 + bn - g0off], nge);
        }
        __syncthreads();
        for (int i = tid; i < 1280; i += 256) {
            int pos = (i < 640);
            int rr = pos ? i : i - 640;
            int lseg = rr / 10, tb = rr % 10;
            int seg = l0 + lseg;
            int tt = base * 4 + (pos ? 0 : 2) + d;
            float rsf = (float)srs[lseg];
            out[TH_OFF + ((size_t)(bg * NSEG + seg) * 3 + c) * 80 + tt * 10 + tb] =
                (float)hist[i] / (24.0f * rsf);
        }
    } else {
        // ch-final: one seg per block; partials staged to LDS in parallel.
        __shared__ unsigned crs[CHP];
        __shared__ int sxm[CHP], sxM[CHP], sym[CHP], syM[CHP];
        int seg = bx - 288;                // [0,1536)
        int bg = seg >> 8;
        int s = seg & 255;
        if (tid < CHP) crs[tid] = rsp[((size_t)(bg * CHP + tid)) * NSEG + s];
        else if (tid < 2 * CHP) sxm[tid - CHP] = bxmin[((size_t)(bg * CHP + tid - CHP)) * NSEG + s];
        else if (tid < 3 * CHP) sxM[tid - 2 * CHP] = bxmax[((size_t)(bg * CHP + tid - 2 * CHP)) * NSEG + s];
        else if (tid < 4 * CHP) sym[tid - 3 * CHP] = bymin[((size_t)(bg * CHP + tid - 3 * CHP)) * NSEG + s];
        else if (tid < 5 * CHP) syM[tid - 4 * CHP] = bymax[((size_t)(bg * CHP + tid - 4 * CHP)) * NSEG + s];
        __syncthreads();
        if (tid < 75) {
            unsigned rs = 0;
            #pragma unroll 4
            for (int p = 0; p < CHP; ++p) rs += crs[p];
            float rsf = (float)rs;
            int c = tid / 25, cb = tid - c * 25;
            int bin = s * 25 + cb;
            unsigned sum = 0;
            #pragma unroll 4
            for (int p = 0; p < CHP; ++p) {
                unsigned v = chp_w[((size_t)((bg * 3 + c) * CHP + p)) * 3200 + (bin >> 1)];
                sum += (v >> ((bin & 1) << 4)) & 0xFFFFu;
            }
            out[CH_OFF + (size_t)seg * 75 + tid] = (float)sum / (3.0f * rsf);
        } else if (tid == 75) {
            unsigned rs = 0;
            #pragma unroll 4
            for (int p = 0; p < CHP; ++p) rs += crs[p];
            float rsf = (float)rs;
            out[seg] = rsf;
            int xmn = INT_MAX, xmx = INT_MIN, ymn = INT_MAX, ymx = INT_MIN;
            #pragma unroll 4
            for (int p = 0; p < CHP; ++p) {
                xmn = min(xmn, sxm[p]); xmx = max(xmx, sxM[p]);
                ymn = min(ymn, sym[p]); ymx = max(ymx, syM[p]);
            }
            if (!(rsf > 0.f)) { xmn = IW; ymn = IW; xmx = 0; ymx = 0; }
            float* xy = out + XY_OFF + (size_t)seg * 4;
            xy[0] = (float)xmn; xy[1] = (float)ymn;
            xy[2] = (float)(xmx - xmn); xy[3] = (float)(ymx - ymn);
        }
    }
}

extern "C" void kernel_launch(void* const* d_in, const int* in_sizes, int n_in,
                              void* d_out, int out_size, void* d_ws, size_t ws_size,
                              hipStream_t stream) {
    const float* img = (const float*)d_in[0];
    const int* lab = (const int*)d_in[1];
    float* out = (float*)d_out;

    float* gmaps = (float*)d_ws;                        // 24 maps * 262144 f32 (25.2 MB)
    float* pmin = gmaps + (size_t)24 * HW;              // 24*NBLK
    float* pmax = pmin + 24 * NBLK;
    unsigned* thp_w = (unsigned*)(pmax + 24 * NBLK);    // 72*THP*2560 u32 (~17.7 MB, u16-packed)
    unsigned* chp_w = thp_w + (size_t)72 * THP * 2560;  // 18*CHP*3200 u32 (~7.4 MB, u16-packed)
    unsigned char* lab8 = (unsigned char*)(chp_w + (size_t)18 * CHP * 3200);  // 6*HW u8
    unsigned* rsp = (unsigned*)(lab8 + (size_t)6 * HW); // 6*CHP*256 u32
    int* bxmin = (int*)(rsp + 6 * CHP * NSEG);
    int* bxmax = bxmin + 6 * CHP * NSEG;
    int* bymin = bxmax + 6 * CHP * NSEG;
    int* bymax = bymin + 6 * CHP * NSEG;

    hipLaunchKernelGGL(k_front, dim3(2112), dim3(256), 0, stream,
                       img, lab, gmaps, pmin, pmax, lab8, chp_w, rsp, bxmin, bxmax, bymin, bymax);
    hipLaunchKernelGGL(k_thist, dim3(THP, 72), dim3(256), 0, stream, gmaps, lab8, pmin, pmax, thp_w);
    hipLaunchKernelGGL(k_final, dim3(288 + 1536), dim3(256), 0, stream,
                       thp_w, chp_w, rsp, bxmin, bxmax, bymin, bymax, pmin, pmax, out);
}

// Round 8
// 116.539 us; speedup vs baseline: 2.1112x; 1.0290x over previous
//
#include <hip/hip_runtime.h>
#include <climits>

#define HW 262144          // 512*512
#define IW 512
#define RN 725             // virtual rotated canvas side
#define NSEG 256
#define CH_OFF 1536
#define TH_OFF 116736
#define XY_OFF 485376
#define NBLK 256           // grad tiles per plane; minmax partial count
#define THP 24             // pixel splits in thist
#define CHP 32             // pixel splits in regchist role

// grad tile geometry (r16): output tile 64x16; rotated source box 24x72 at (-156,-156).
#define ASTR 67
#define RSTR 73
#define ROFF 156

static __device__ __forceinline__ float rtap_l(const float* __restrict__ Rt,
                                               int rx0, int ry0, int cx, int cy) {
    if (cx < 0 || cx >= RN || cy < 0 || cy >= RN) return 0.f;
    const float cs = 0.7071067811865476f;
    float xg = (float)cx - 362.0f;
    float yg = (float)cy - 362.0f;
    float xi = cs * xg - cs * yg + 255.5f;
    float yi = cs * xg + cs * yg + 255.5f;
    int xs = (int)rintf(xi);
    int ys = (int)rintf(yi);
    if (xs < 0 || xs >= IW || ys < 0 || ys >= IW) return 0.f;
    return Rt[(ys - ry0) * RSTR + (xs - rx0)];
}

// block-level min/max of map m's NBLK partials; all threads get (mn,mx)
static __device__ __forceinline__ void mm_of_map(const float* __restrict__ pmin,
                                                 const float* __restrict__ pmax,
                                                 int m, float* slo, float* shi,
                                                 float& mn, float& mx) {
    int tid = threadIdx.x;
    float lo = 3.4e38f, hi = -3.4e38f;
    for (int i = tid; i < NBLK; i += 256) {
        lo = fminf(lo, pmin[m * NBLK + i]);
        hi = fmaxf(hi, pmax[m * NBLK + i]);
    }
    slo[tid] = lo; shi[tid] = hi;
    __syncthreads();
    for (int off = 128; off > 0; off >>= 1) {
        if (tid < off) {
            slo[tid] = fminf(slo[tid], slo[tid + off]);
            shi[tid] = fmaxf(shi[tid], shi[tid + off]);
        }
        __syncthreads();
    }
    mn = slo[0]; mx = shi[0];
    __syncthreads();
}

// ==== K1 (r21, unchanged): grad (1536) || packed-regchist (576), 8:3 mod-11 ====
__global__ __launch_bounds__(256) void k_front(
    const float* __restrict__ img, const int* __restrict__ lab,
    float* __restrict__ gmaps, float* __restrict__ pmin, float* __restrict__ pmax,
    unsigned char* __restrict__ lab8, unsigned* __restrict__ chp_w,
    unsigned* __restrict__ rsp, int* __restrict__ bxmin, int* __restrict__ bxmax,
    int* __restrict__ bymin, int* __restrict__ bymax)
{
    __shared__ __align__(16) unsigned char smem[20480];
    int bxid = blockIdx.x;
    int tid = threadIdx.x;
    int grp = bxid / 11, rem = bxid % 11;   // 2112 = 192*11
    if (rem < 8) {
        // ---- grad role: u in [0,1536): tile (u&255), plane bc=(u>>8) ----
        int u = grp * 8 + rem;
        int tile = u & 255;
        int bc = u >> 8;
        float* At = (float*)smem;                               // 1206 f
        float* Rt = At + 18 * ASTR;                             // 1752 f
        float (*slo)[256] = (float (*)[256])(Rt + 24 * RSTR);   // 4*256 f
        float (*shi)[256] = slo + 4;                            // 4*256 f (20024 B)
        // u8 label pack for k_thist: 256 blocks/plane * 256 thr * 4 == HW
        {
            int i = tile * 256 + tid;
            int4 l = ((const int4*)(lab + (size_t)bc * HW))[i];
            unsigned v = (unsigned)(l.x & 255) | ((unsigned)(l.y & 255) << 8) |
                         ((unsigned)(l.z & 255) << 16) | ((unsigned)(l.w & 255) << 24);
            ((unsigned*)(lab8 + (size_t)bc * HW))[i] = v;
        }
        int tx0 = (tile & 7) << 6;
        int ty0 = (tile >> 3) << 4;
        const float* im = img + (size_t)bc * HW;
        int lane = tid & 63, wr = tid >> 6;
        for (int r = wr; r < 18; r += 4) {
            int gy = ty0 - 1 + r;
            bool yok = (gy >= 0 && gy < IW);
            int gx = tx0 - 1 + lane;
            At[r * ASTR + lane] = (yok && gx >= 0 && gx < IW) ? im[gy * IW + gx] : 0.f;
            if (lane < 2) {
                int gx2 = gx + 64;
                At[r * ASTR + lane + 64] = (yok && gx2 >= 0 && gx2 < IW) ? im[gy * IW + gx2] : 0.f;
            }
        }
        for (int r = wr; r < 24; r += 4) {
            int gy = ty0 - ROFF + r;
            bool yok = (gy >= 0 && gy < IW);
            int gx = tx0 - ROFF + lane;
            Rt[r * RSTR + lane] = (yok && gx >= 0 && gx < IW) ? im[gy * IW + gx] : 0.f;
            if (lane < 8) {
                int gx2 = gx + 64;
                Rt[r * RSTR + lane + 64] = (yok && gx2 >= 0 && gx2 < IW) ? im[gy * IW + gx2] : 0.f;
            }
        }
        __syncthreads();
        const float cs = 0.7071067811865476f;
        int rx0 = tx0 - ROFF, ry0 = ty0 - ROFF;
        float mn0 = 3.4e38f, mx0 = -3.4e38f, mn1 = 3.4e38f, mx1 = -3.4e38f;
        float mn2 = 3.4e38f, mx2 = -3.4e38f, mn3 = 3.4e38f, mx3 = -3.4e38f;
        #pragma unroll
        for (int it = 0; it < 4; ++it) {
            int ly = wr * 4 + it;
            int x = tx0 + lane, y = ty0 + ly;
            int p = y * IW + x;
            const float* Ar = At + ly * ASTR + lane;
            float a  = Ar[0],            b2 = Ar[1],            c2 = Ar[2];
            float d2 = Ar[ASTR],                                 e2 = Ar[ASTR + 2];
            float f2 = Ar[2 * ASTR],     h2 = Ar[2 * ASTR + 1], i9 = Ar[2 * ASTR + 2];
            float g0 = -3.f*a + 3.f*c2 + 10.f*d2 + 10.f*e2 - 3.f*f2 + 3.f*i9;
            float g1 = -3.f*a + 10.f*b2 - 3.f*c2 + 3.f*f2 + 10.f*h2 + 3.f*i9;
            gmaps[((size_t)(bc*2+0))*HW + p] = g0;
            gmaps[((size_t)(bc*2+1))*HW + p] = g1;
            float xgc = (float)(x + 105) - 512.5f;
            float ygc = (float)(y + 105) - 512.5f;
            float t1 = cs * xgc, t2 = cs * ygc;
            float xi = (t1 + t2) + 362.0f;
            float yi = (-t1 + t2) + 362.0f;
            int xn = (int)rintf(xi);
            int yn = (int)rintf(yi);
            float r0 = 0.f, r1 = 0.f;
            if (xn >= 0 && xn < RN && yn >= 0 && yn < RN) {
                float ra = rtap_l(Rt, rx0, ry0, xn-1, yn-1);
                float rb = rtap_l(Rt, rx0, ry0, xn,   yn-1);
                float rc = rtap_l(Rt, rx0, ry0, xn+1, yn-1);
                float rd = rtap_l(Rt, rx0, ry0, xn-1, yn);
                float re = rtap_l(Rt, rx0, ry0, xn+1, yn);
                float rf = rtap_l(Rt, rx0, ry0, xn-1, yn+1);
                float rh = rtap_l(Rt, rx0, ry0, xn,   yn+1);
                float ri = rtap_l(Rt, rx0, ry0, xn+1, yn+1);
                r0 = -3.f*ra + 3.f*rc + 10.f*rd + 10.f*re - 3.f*rf + 3.f*ri;
                r1 = -3.f*ra + 10.f*rb - 3.f*rc + 3.f*rf + 10.f*rh + 3.f*ri;
            }
            gmaps[((size_t)(12 + bc*2+0))*HW + p] = r0;
            gmaps[((size_t)(12 + bc*2+1))*HW + p] = r1;
            mn0 = fminf(mn0, g0); mx0 = fmaxf(mx0, g0);
            mn1 = fminf(mn1, g1); mx1 = fmaxf(mx1, g1);
            mn2 = fminf(mn2, r0); mx2 = fmaxf(mx2, r0);
            mn3 = fminf(mn3, r1); mx3 = fmaxf(mx3, r1);
        }
        slo[0][tid] = mn0; shi[0][tid] = mx0;
        slo[1][tid] = mn1; shi[1][tid] = mx1;
        slo[2][tid] = mn2; shi[2][tid] = mx2;
        slo[3][tid] = mn3; shi[3][tid] = mx3;
        __syncthreads();
        for (int off = 128; off > 0; off >>= 1) {
            if (tid < off) {
                #pragma unroll
                for (int k = 0; k < 4; ++k) {
                    slo[k][tid] = fminf(slo[k][tid], slo[k][tid + off]);
                    shi[k][tid] = fmaxf(shi[k][tid], shi[k][tid + off]);
                }
            }
            __syncthreads();
        }
        if (tid < 4) {
            int m = (tid < 2) ? (bc*2 + tid) : (12 + bc*2 + (tid - 2));
            pmin[m * NBLK + tile] = slo[tid][0];
            pmax[m * NBLK + tile] = shi[tid][0];
        }
    } else {
        // ---- packed regchist role: w in [0,576): row gy=w>>5, split sp=w&31 ----
        int w = grp * 3 + (rem - 8);
        int gy = w >> 5;           // (b*3+g)*3 + c
        int sp = w & 31;
        int c = gy % 3;
        int bg = gy / 3;
        int b = bg / 3;
        unsigned* pk = (unsigned*)smem;             // 3200 words (6400 u16 bins)
        unsigned* prc = pk + 3200;                  // 128 words (256 u16 rcnt)
        int* sxmin = (int*)(prc + 128);             // 4x256 int (17408 B total)
        int* sxmax = sxmin + NSEG;
        int* symin = sxmax + NSEG;
        int* symax = symin + NSEG;
        bool do_reg = (c == 0);
        for (int i = tid; i < 3200; i += 256) pk[i] = 0;
        if (do_reg) {
            if (tid < 128) prc[tid] = 0;
            sxmin[tid] = INT_MAX; sxmax[tid] = INT_MIN;
            symin[tid] = INT_MAX; symax[tid] = INT_MIN;
        }
        __syncthreads();
        const float4* ip = (const float4*)(img + ((size_t)b * 3 + c) * HW);
        const int4* lp = (const int4*)(lab + (size_t)bg * HW);
        for (int i = sp * 256 + tid; i < HW / 4; i += 256 * CHP) {
            float4 v4 = ip[i];
            int4 l4 = lp[i];
            int l0 = l4.x & 255, l1 = l4.y & 255, l2 = l4.z & 255, l3 = l4.w & 255;
            int b0 = (int)((float)l0 * 25.0f + v4.x * 24.0f);
            int b1 = (int)((float)l1 * 25.0f + v4.y * 24.0f);
            int b2 = (int)((float)l2 * 25.0f + v4.z * 24.0f);
            int b3 = (int)((float)l3 * 25.0f + v4.w * 24.0f);
            b0 = min(max(b0, 0), 6399); b1 = min(max(b1, 0), 6399);
            b2 = min(max(b2, 0), 6399); b3 = min(max(b3, 0), 6399);
            atomicAdd(&pk[b0 >> 1], 1u << ((b0 & 1) << 4));
            atomicAdd(&pk[b1 >> 1], 1u << ((b1 & 1) << 4));
            atomicAdd(&pk[b2 >> 1], 1u << ((b2 & 1) << 4));
            atomicAdd(&pk[b3 >> 1], 1u << ((b3 & 1) << 4));
            if (do_reg) {
                int p = i << 2;
                int y = p >> 9, x = p & 511;
                atomicAdd(&prc[l0 >> 1], 1u << ((l0 & 1) << 4));
                atomicAdd(&prc[l1 >> 1], 1u << ((l1 & 1) << 4));
                atomicAdd(&prc[l2 >> 1], 1u << ((l2 & 1) << 4));
                atomicAdd(&prc[l3 >> 1], 1u << ((l3 & 1) << 4));
                atomicMin(&sxmin[l0], x);     atomicMax(&sxmax[l0], x);
                atomicMin(&sxmin[l1], x + 1); atomicMax(&sxmax[l1], x + 1);
                atomicMin(&sxmin[l2], x + 2); atomicMax(&sxmax[l2], x + 2);
                atomicMin(&sxmin[l3], x + 3); atomicMax(&sxmax[l3], x + 3);
                atomicMin(&symin[l0], y); atomicMax(&symax[l0], y);
                atomicMin(&symin[l1], y); atomicMax(&symax[l1], y);
                atomicMin(&symin[l2], y); atomicMax(&symax[l2], y);
                atomicMin(&symin[l3], y); atomicMax(&symax[l3], y);
            }
        }
        __syncthreads();
        unsigned* dst = chp_w + ((size_t)gy * CHP + sp) * 3200;
        for (int i = tid; i < 3200; i += 256) dst[i] = pk[i];
        if (do_reg) {
            size_t pi = (size_t)(bg * CHP + sp) * NSEG + tid;
            rsp[pi] = (prc[tid >> 1] >> ((tid & 1) << 4)) & 0xFFFFu;
            bxmin[pi] = sxmin[tid]; bxmax[pi] = sxmax[tid];
            bymin[pi] = symin[tid]; bymax[pi] = symax[tid];
        }
    }
}

// ==== K2 (r22): thist (1728, r21 body) || ch-final+rs+xywh riders (768) ====
// ch-final depends only on K1 -> rides K2's scheduling bubbles instead of
// waiting for K2 to drain (it was the K3 half with no K2 dependency).
__global__ __launch_bounds__(256) void k_hist(
    const float* __restrict__ maps, const unsigned char* __restrict__ lab8,
    const float* __restrict__ pmin, const float* __restrict__ pmax,
    unsigned* __restrict__ thp_w, const unsigned* __restrict__ chp_w,
    const unsigned* __restrict__ rsp,
    const int* __restrict__ bxmin, const int* __restrict__ bxmax,
    const int* __restrict__ bymin, const int* __restrict__ bymax,
    float* __restrict__ out)
{
    __shared__ __align__(16) unsigned char smem[22528];
    int bx = blockIdx.x;
    int tid = threadIdx.x;
    if (bx < 1728) {
        // ---- thist role ----
        unsigned* cnt = (unsigned*)smem;            // 5120 u32
        float* slo = (float*)(smem + 20480);
        float* shi = slo + 256;
        int gy = bx / THP;
        int split = bx - gy * THP;
        int gi = gy % 3;
        int r = gy / 3;
        int base = r & 1;
        int bd = r >> 1;
        int d = bd & 1;
        int bc = bd >> 1;
        int b = bc / 3;
        int m = base * 12 + bc * 2 + d;
        float mn, mx;
        mm_of_map(pmin, pmax, m, slo, shi, mn, mx);
        for (int i = tid; i < 5120; i += 256) cnt[i] = 0;
        __syncthreads();
        float hminp = fmaxf(mn, 0.f), denp = fmaxf(mx, 0.f) - hminp;
        float hminn = fminf(mn, 0.f), denn = fminf(mx, 0.f) - hminn;
        const float4* src = (const float4*)(maps + (size_t)m * HW);
        const unsigned* lp = (const unsigned*)(lab8 + (size_t)(b * 3 + gi) * HW);
        for (int i = split * 256 + tid; i < HW / 4; i += 256 * THP) {
            float4 v4 = src[i];
            unsigned l4 = lp[i];
#define TH1(V, SH)                                                     \
            {                                                          \
                float v = (V);                                         \
                bool ge = (v >= 0.f);                                  \
                float hm = ge ? hminp : hminn;                         \
                float dn = ge ? denp : denn;                           \
                float t9 = ((v - hm) / dn) * 9.0f;                     \
                int bi = (int)((float)((l4 >> SH) & 255u) * 10.0f + t9); \
                bi = min(max(bi, 0), 2559);                            \
                atomicAdd(&cnt[(ge ? 0 : 2560) + bi], 1u);             \
            }
            TH1(v4.x, 0) TH1(v4.y, 8) TH1(v4.z, 16) TH1(v4.w, 24)
#undef TH1
        }
        __syncthreads();
        unsigned* dst = thp_w + ((size_t)(gy * THP + split)) * 2560;
        for (int i = tid; i < 2560; i += 256)
            dst[i] = cnt[2 * i] | (cnt[2 * i + 1] << 16);
    } else {
        // ---- ch-final rider: 2 segs per block, LDS-staged parallel reduce ----
        unsigned (*crs)[32] = (unsigned (*)[32])smem;       // [2][32]
        int (*sxm)[32] = (int (*)[32])(smem + 256);
        int (*sxM)[32] = (int (*)[32])(smem + 512);
        int (*sym)[32] = (int (*)[32])(smem + 768);
        int (*syM)[32] = (int (*)[32])(smem + 1024);
        int j = bx - 1728;                 // [0,768)
        int seg0 = j * 2;
        int bg = seg0 >> 8;
        int s0 = seg0 & 255, s1 = s0 + 1;
        int g = tid >> 5, w = tid & 31;
        size_t base0 = (size_t)(bg * CHP + w) * NSEG;
        if (g == 0)      crs[0][w] = rsp[base0 + s0];
        else if (g == 1) sxm[0][w] = bxmin[base0 + s0];
        else if (g == 2) sxM[0][w] = bxmax[base0 + s0];
        else if (g == 3) sym[0][w] = bymin[base0 + s0];
        else if (g == 4) syM[0][w] = bymax[base0 + s0];
        else if (g == 5) crs[1][w] = rsp[base0 + s1];
        else if (g == 6) sxm[1][w] = bxmin[base0 + s1];
        else if (g == 7) sxM[1][w] = bxmax[base0 + s1];
        if (g == 0)      sym[1][w] = bymin[base0 + s1];
        else if (g == 1) syM[1][w] = bymax[base0 + s1];
        __syncthreads();
        int half = tid >> 7, t2 = tid & 127;
        int s = half ? s1 : s0;
        int seg = seg0 + half;
        if (t2 < 75) {
            unsigned rs = 0;
            #pragma unroll 4
            for (int p = 0; p < CHP; ++p) rs += crs[half][p];
            float rsf = (float)rs;
            int c = t2 / 25, cb = t2 - c * 25;
            int bin = s * 25 + cb;
            unsigned sum = 0;
            #pragma unroll 4
            for (int p = 0; p < CHP; ++p) {
                unsigned v = chp_w[((size_t)((bg * 3 + c) * CHP + p)) * 3200 + (bin >> 1)];
                sum += (v >> ((bin & 1) << 4)) & 0xFFFFu;
            }
            out[CH_OFF + (size_t)seg * 75 + t2] = (float)sum / (3.0f * rsf);
        } else if (t2 == 75) {
            unsigned rs = 0;
            #pragma unroll 4
            for (int p = 0; p < CHP; ++p) rs += crs[half][p];
            float rsf = (float)rs;
            out[seg] = rsf;
            int xmn = INT_MAX, xmx = INT_MIN, ymn = INT_MAX, ymx = INT_MIN;
            #pragma unroll 4
            for (int p = 0; p < CHP; ++p) {
                xmn = min(xmn, sxm[half][p]); xmx = max(xmx, sxM[half][p]);
                ymn = min(ymn, sym[half][p]); ymx = max(ymx, syM[half][p]);
            }
            if (!(rsf > 0.f)) { xmn = IW; ymn = IW; xmx = 0; ymx = 0; }
            float* xy = out + XY_OFF + (size_t)seg * 4;
            xy[0] = (float)xmn; xy[1] = (float)ymn;
            xy[2] = (float)(xmx - xmn); xy[3] = (float)(ymx - ymn);
        }
    }
}

// ==== K3 (r22): pure th-reduce, 576 blocks (32-label chunks) ====
// Sign-completion bins are within the label's own 10-bin range (mn<0<mx for
// every Scharr map: tp0=0, tn0=9) -> chunk-local; guard keeps exactness.
__global__ __launch_bounds__(256) void k_final(
    const unsigned* __restrict__ thp_w, const unsigned* __restrict__ rsp,
    const float* __restrict__ pmin, const float* __restrict__ pmax,
    float* __restrict__ out)
{
    __shared__ unsigned hist[640];     // [0,320) pos bins, [320,640) neg, 32 labels
    __shared__ unsigned srs[32];
    __shared__ float slo[256], shi[256];
    int tid = threadIdx.x;
    int bx = blockIdx.x;
    int gy = bx >> 3;
    int ck = bx & 7;
    int l0 = ck << 5;                  // first label of chunk
    int gi = gy % 3; int r = gy / 3; int base = r & 1;
    int bd = r >> 1; int d = bd & 1; int bc = bd >> 1;
    int b = bc / 3, c = bc - b * 3;
    int m = base * 12 + bc * 2 + d;
    int bg = b * 3 + gi;
    float mn, mx;
    mm_of_map(pmin, pmax, m, slo, shi, mn, mx);
    // reduce packed partials: 160 words/side for this chunk
    for (int w = tid; w < 320; w += 256) {
        int gw = (w < 160) ? (l0 * 5 + w) : (1280 + l0 * 5 + (w - 160));
        unsigned s0 = 0, s1 = 0;
        #pragma unroll 4
        for (int p = 0; p < THP; ++p) {
            unsigned v = thp_w[((size_t)(gy * THP + p)) * 2560 + gw];
            s0 += v & 0xFFFFu; s1 += v >> 16;
        }
        int bi = (w < 160) ? (2 * w) : (320 + 2 * (w - 160));
        hist[bi] = s0; hist[bi + 1] = s1;
    }
    if (tid < 32) {
        unsigned s = 0;
        #pragma unroll 4
        for (int p = 0; p < CHP; ++p) s += rsp[((size_t)(bg * CHP + p)) * NSEG + l0 + tid];
        srs[tid] = s;
    }
    __syncthreads();
    if (tid < 32) {
        int l = l0 + tid;   // this chunk's labels: sign-completion
        unsigned nge = 0;
        for (int tb = 0; tb < 10; ++tb) nge += hist[tid * 10 + tb];  // v>=0 count
        unsigned rsu = srs[tid];
        unsigned nlt = (rsu >= nge) ? (rsu - nge) : 0u;              // v<0 count
        float hminp = fmaxf(mn, 0.f), denp = fmaxf(mx, 0.f) - hminp;
        float hminn = fminf(mn, 0.f), denn = fminf(mx, 0.f) - hminn;
        float la = (float)l;
        float tp0 = ((0.0f - hminp) / denp) * 9.0f;  // pos bin of clipped (v<0)
        float tn0 = ((0.0f - hminn) / denn) * 9.0f;  // neg bin of clipped (v>=0)
        int g0off = l0 * 10;
        int bp = (int)(la * 10.0f + tp0); bp = min(max(bp, 0), 2559);
        int bn = (int)(la * 10.0f + tn0); bn = min(max(bn, 0), 2559);
        if (nlt && bp >= g0off && bp < g0off + 320) atomicAdd(&hist[bp - g0off], nlt);
        if (nge && bn >= g0off && bn < g0off + 320) atomicAdd(&hist[320 + bn - g0off], nge);
    }
    __syncthreads();
    for (int i = tid; i < 640; i += 256) {
        int pos = (i < 320);
        int rr = pos ? i : i - 320;
        int lseg = rr / 10, tb = rr % 10;
        int seg = l0 + lseg;
        int tt = base * 4 + (pos ? 0 : 2) + d;
        float rsf = (float)srs[lseg];
        out[TH_OFF + ((size_t)(bg * NSEG + seg) * 3 + c) * 80 + tt * 10 + tb] =
            (float)hist[i] / (24.0f * rsf);
    }
}

extern "C" void kernel_launch(void* const* d_in, const int* in_sizes, int n_in,
                              void* d_out, int out_size, void* d_ws, size_t ws_size,
                              hipStream_t stream) {
    const float* img = (const float*)d_in[0];
    const int* lab = (const int*)d_in[1];
    float* out = (float*)d_out;

    float* gmaps = (float*)d_ws;                        // 24 maps * 262144 f32 (25.2 MB)
    float* pmin = gmaps + (size_t)24 * HW;              // 24*NBLK
    float* pmax = pmin + 24 * NBLK;
    unsigned* thp_w = (unsigned*)(pmax + 24 * NBLK);    // 72*THP*2560 u32 (~17.7 MB, u16-packed)
    unsigned* chp_w = thp_w + (size_t)72 * THP * 2560;  // 18*CHP*3200 u32 (~7.4 MB, u16-packed)
    unsigned char* lab8 = (unsigned char*)(chp_w + (size_t)18 * CHP * 3200);  // 6*HW u8
    unsigned* rsp = (unsigned*)(lab8 + (size_t)6 * HW); // 6*CHP*256 u32
    int* bxmin = (int*)(rsp + 6 * CHP * NSEG);
    int* bxmax = bxmin + 6 * CHP * NSEG;
    int* bymin = bxmax + 6 * CHP * NSEG;
    int* bymax = bymin + 6 * CHP * NSEG;

    hipLaunchKernelGGL(k_front, dim3(2112), dim3(256), 0, stream,
                       img, lab, gmaps, pmin, pmax, lab8, chp_w, rsp, bxmin, bxmax, bymin, bymax);
    hipLaunchKernelGGL(k_hist, dim3(1728 + 768), dim3(256), 0, stream,
                       gmaps, lab8, pmin, pmax, thp_w, chp_w, rsp, bxmin, bxmax, bymin, bymax, out);
    hipLaunchKernelGGL(k_final, dim3(576), dim3(256), 0, stream,
                       thp_w, rsp, pmin, pmax, out);
}